// Round 2
// baseline (816.503 us; speedup 1.0000x reference)
//
#include <hip/hip_runtime.h>
#include <cstdint>
#include <cstddef>

#define DEVI static __device__ __forceinline__

typedef __bf16 bf16x8 __attribute__((ext_vector_type(8)));
typedef float f32x4 __attribute__((ext_vector_type(4)));
typedef unsigned short u16;
typedef unsigned int u32;

DEVI float b2f(u16 h){ u32 x = ((u32)h) << 16; float f; __builtin_memcpy(&f, &x, 4); return f; }
DEVI u16 f2b(float f){ u32 x; __builtin_memcpy(&x, &f, 4); u32 r = (x + 0x7FFFu + ((x >> 16) & 1u)) >> 16; return (u16)r; }

union V16 { uint4 u; bf16x8 v; u16 h[8]; };

DEVI bf16x8 ld16(const u16* p){ V16 t; t.u = *(const uint4*)p; return t.v; }
DEVI f32x4 fzero(){ f32x4 z; z[0]=0.f; z[1]=0.f; z[2]=0.f; z[3]=0.f; return z; }
DEVI f32x4 mm(bf16x8 a, bf16x8 b, f32x4 c){ return __builtin_amdgcn_mfma_f32_16x16x32_bf16(a, b, c, 0, 0, 0); }
DEVI uint4 cvt8(const float* p){
  float4 a = *(const float4*)p, b = *(const float4*)(p + 4);
  V16 t; t.h[0]=f2b(a.x); t.h[1]=f2b(a.y); t.h[2]=f2b(a.z); t.h[3]=f2b(a.w);
  t.h[4]=f2b(b.x); t.h[5]=f2b(b.y); t.h[6]=f2b(b.z); t.h[7]=f2b(b.w); return t.u;
}

// ---------------- LayerNorm (f32 in -> bf16 out) ----------------
__global__ __launch_bounds__(256) void k_ln_src(const float* __restrict__ in, const float* __restrict__ w,
                                                const float* __restrict__ bias, u16* __restrict__ out){
  int wave = threadIdx.x >> 6, lane = threadIdx.x & 63;
  int row = blockIdx.x * 4 + wave;            // 8192 rows
  const float* p = in + (size_t)row * 384;
  float v[6], s = 0.f, sq = 0.f;
  for(int i = 0; i < 6; i++){ v[i] = p[lane + 64*i]; s += v[i]; sq += v[i]*v[i]; }
  for(int off = 1; off < 64; off <<= 1){ s += __shfl_xor(s, off); sq += __shfl_xor(sq, off); }
  float mu = s * (1.f/384.f), var = sq * (1.f/384.f) - mu*mu;
  float rstd = rsqrtf(fmaxf(var, 0.f) + 1e-5f);
  for(int i = 0; i < 6; i++){
    int j = lane + 64*i;
    out[(size_t)row*384 + j] = f2b((v[i]-mu)*rstd*w[j] + bias[j]);
  }
}

// ---------------- LayerNorm (f32 in -> bf16 + f32 out) ----------------
__global__ __launch_bounds__(256) void k_ln_mid(const float* __restrict__ in, const float* __restrict__ w,
                                                const float* __restrict__ bias, u16* __restrict__ outb,
                                                float* __restrict__ outf){
  int wave = threadIdx.x >> 6, lane = threadIdx.x & 63;
  int row = blockIdx.x * 4 + wave;
  const float* p = in + (size_t)row * 384;
  float v[6], s = 0.f, sq = 0.f;
  for(int i = 0; i < 6; i++){ v[i] = p[lane + 64*i]; s += v[i]; sq += v[i]*v[i]; }
  for(int off = 1; off < 64; off <<= 1){ s += __shfl_xor(s, off); sq += __shfl_xor(sq, off); }
  float mu = s * (1.f/384.f), var = sq * (1.f/384.f) - mu*mu;
  float rstd = rsqrtf(fmaxf(var, 0.f) + 1e-5f);
  for(int i = 0; i < 6; i++){
    int j = lane + 64*i;
    float o = (v[i]-mu)*rstd*w[j] + bias[j];
    outb[(size_t)row*384 + j] = f2b(o);
    outf[(size_t)row*384 + j] = o;
  }
}

// ---------------- bf16 MFMA GEMM: C = A[M,K](bf16) @ W[N,K](f32->bf16)^T + bias ----------------
// MODE 0: scatter qkv -> q/k/v [B,H,N,64] bf16
// MODE 1: + res (f32) -> f32 out
// MODE 2: exact GELU -> bf16 out
template<int MODE, int KDIM, int NOUT>
__global__ __launch_bounds__(256,2) void k_gemm(
    const u16* __restrict__ A, const float* __restrict__ W, const float* __restrict__ bias,
    u16* __restrict__ o0, u16* __restrict__ o1, u16* __restrict__ o2,
    const float* __restrict__ res, float* __restrict__ fout)
{
  __shared__ __align__(16) u16 As[128][72];   // +8 pad breaks bank conflicts
  __shared__ __align__(16) u16 Bs[128][72];
  const int tid = threadIdx.x, wv = tid >> 6, lane = tid & 63, quad = lane >> 4, l15 = lane & 15;
  constexpr int NB = NOUT / 128;
  const int m0 = (blockIdx.x / NB) * 128, n0 = (blockIdx.x % NB) * 128;
  const int wr = (wv >> 1) * 64, wc = (wv & 1) * 64;
  f32x4 acc[4][4];
  for(int i = 0; i < 4; i++) for(int j = 0; j < 4; j++) acc[i][j] = fzero();
  for(int kt = 0; kt < KDIM; kt += 64){
    for(int i = 0; i < 4; i++){
      int c = tid + i*256; int row = c >> 3, col = (c & 7) * 8;
      *(uint4*)&As[row][col] = *(const uint4*)&A[(size_t)(m0+row)*KDIM + kt + col];
      *(uint4*)&Bs[row][col] = cvt8(&W[(size_t)(n0+row)*KDIM + kt + col]);
    }
    __syncthreads();
    for(int hf = 0; hf < 2; hf++){
      bf16x8 af[4], bf_[4];
      for(int t = 0; t < 4; t++) af[t]  = ld16(&As[wr + t*16 + l15][hf*32 + quad*8]);
      for(int t = 0; t < 4; t++) bf_[t] = ld16(&Bs[wc + t*16 + l15][hf*32 + quad*8]);
      for(int mt = 0; mt < 4; mt++) for(int nt = 0; nt < 4; nt++)
        acc[mt][nt] = mm(af[mt], bf_[nt], acc[mt][nt]);
    }
    __syncthreads();
  }
  for(int mt = 0; mt < 4; mt++) for(int nt = 0; nt < 4; nt++){
    const int gcol = n0 + wc + nt*16 + l15;
    const float bv = bias[gcol];
    for(int r = 0; r < 4; r++){
      const int grow = m0 + wr + mt*16 + quad*4 + r;
      float val = acc[mt][nt][r] + bv;
      if constexpr(MODE == 0){
        int s = gcol / 384, rem = gcol - s*384, h = rem >> 6, d = rem & 63;
        int bb = grow >> 9, n = grow & 511;
        u16* t = (s == 0) ? o0 : ((s == 1) ? o1 : o2);
        t[(((size_t)(bb*6 + h))*512 + n)*64 + d] = f2b(val);
      } else if constexpr(MODE == 1){
        val += res[(size_t)grow*384 + gcol];
        fout[(size_t)grow*384 + gcol] = val;
      } else {
        float g = 0.5f * val * (1.f + erff(val * 0.70710678118654752f));
        o0[(size_t)grow*1152 + gcol] = f2b(g);
      }
    }
  }
}

// ---------------- Cholesky-QR per (b,h): Aq = q * R^{-1}, plus ||row||^4 ----------------
__global__ __launch_bounds__(256,1) void k_cholqr(
    const u16* __restrict__ qb, const u16* __restrict__ kb,
    u16* __restrict__ aqb, u16* __restrict__ akb,
    float* __restrict__ qn4, float* __restrict__ kn4)
{
  __shared__ float G[64][65];
  __shared__ float invd[64];
  const int tid = threadIdx.x, wv = tid >> 6, lane = tid & 63, quad = lane >> 4, l15 = lane & 15;
  const int blk = blockIdx.x;                 // 0..191: first 96 = q, next 96 = k
  const int isk = blk >= 96; const int bh = isk ? blk - 96 : blk;
  const u16* M = (isk ? kb : qb) + (size_t)bh * 512 * 64;
  u16* Ao = (isk ? akb : aqb) + (size_t)bh * 512 * 64;
  float* n4 = (isk ? kn4 : qn4) + bh * 512;
  for(int rr = tid; rr < 512; rr += 256){
    const u16* p = M + (size_t)rr * 64;
    float s = 0.f;
    for(int i = 0; i < 8; i++){ V16 c; c.u = *(const uint4*)&p[i*8];
      for(int j = 0; j < 8; j++){ float x = b2f(c.h[j]); s += x*x; } }
    n4[rr] = s * s;
  }
  // Gram G = M^T M via MFMA (strided gathers; tiny volume)
  f32x4 g4[4];
  for(int jt = 0; jt < 4; jt++) g4[jt] = fzero();
  for(int k0 = 0; k0 < 512; k0 += 32){
    const u16* base = M + (size_t)(k0 + quad*8) * 64;
    V16 a;
    for(int j = 0; j < 8; j++) a.h[j] = base[(size_t)j*64 + wv*16 + l15];
    for(int jt = 0; jt < 4; jt++){
      V16 bb;
      for(int j = 0; j < 8; j++) bb.h[j] = base[(size_t)j*64 + jt*16 + l15];
      g4[jt] = mm(a.v, bb.v, g4[jt]);
    }
  }
  for(int jt = 0; jt < 4; jt++)
    for(int r = 0; r < 4; r++)
      G[wv*16 + quad*4 + r][jt*16 + l15] = g4[jt][r];
  __syncthreads();
  // Cholesky (upper R; guarded pivots)
  for(int k = 0; k < 64; k++){
    if(tid == 0){ float pv = sqrtf(fmaxf(G[k][k], 1e-12f)); G[k][k] = pv; invd[k] = 1.f / pv; }
    __syncthreads();
    if(tid > k && tid < 64) G[k][tid] *= invd[k];
    __syncthreads();
    float gkl = G[k][lane];
    for(int i = k + 1 + wv; i < 64; i += 4)
      G[i][lane] -= G[k][i] * gkl;
    __syncthreads();
  }
  // per-row solve y R = m (forward substitution, fully unrolled)
  for(int rr = tid; rr < 512; rr += 256){
    float m[64];
    const u16* p = M + (size_t)rr * 64;
    for(int i = 0; i < 8; i++){ V16 c; c.u = *(const uint4*)&p[i*8];
      for(int j = 0; j < 8; j++) m[i*8 + j] = b2f(c.h[j]); }
    #pragma unroll
    for(int j = 0; j < 64; j++){
      float yj = m[j] * invd[j];
      m[j] = yj;
      #pragma unroll
      for(int i = j + 1; i < 64; i++) m[i] -= yj * G[j][i];
    }
    for(int i = 0; i < 8; i++){ V16 c;
      for(int j = 0; j < 8; j++) c.h[j] = f2b(m[i*8 + j]);
      *(uint4*)&Ao[(size_t)rr*64 + i*8] = c.u; }
  }
}

// ---------------- Fused logits (eucl+riem+grass, conv-mixed) + softmax -> attn (f32, to d_out) ----------------
__global__ __launch_bounds__(256,2) void k_attn(
    const u16* __restrict__ qb, const u16* __restrict__ kb,
    const u16* __restrict__ aqb, const u16* __restrict__ akb,
    const float* __restrict__ qn4, const float* __restrict__ kn4,
    const float* __restrict__ convw, const float* __restrict__ convb,
    const float* __restrict__ scp, const float* __restrict__ rsp, const float* __restrict__ gsp,
    float* __restrict__ attn)
{
  __shared__ __align__(16) u16 qt[6][16][72];
  __shared__ __align__(16) u16 at[6][16][72];
  __shared__ float cw[108];
  __shared__ float cb[6];
  __shared__ float red[6][16][4];
  const int tid = threadIdx.x, wv = tid >> 6, lane = tid & 63, quad = lane >> 4, l15 = lane & 15;
  const int b = blockIdx.x >> 5, n0 = (blockIdx.x & 31) * 16;
  if(tid < 108) cw[tid] = convw[tid];
  if(tid >= 128 && tid < 134) cb[tid - 128] = convb[tid - 128];
  for(int c = tid; c < 768; c += 256){
    int h = c >> 7, rem = c & 127, row = rem >> 3, col = (rem & 7) * 8;
    size_t off = (((size_t)(b*6 + h)) * 512 + (size_t)(n0 + row)) * 64 + col;
    *(uint4*)&qt[h][row][col] = *(const uint4*)&qb[off];
    *(uint4*)&at[h][row][col] = *(const uint4*)&aqb[off];
  }
  __syncthreads();
  const float sc = scp[0], rs = rsp[0], gs = gsp[0];
  float qn4r[6][4];
  for(int h = 0; h < 6; h++)
    for(int r = 0; r < 4; r++)
      qn4r[h][r] = qn4[(b*6 + h)*512 + n0 + quad*4 + r];
  float S[6][4], recS[6][4];
  for(int o = 0; o < 6; o++) for(int r = 0; r < 4; r++) S[o][r] = 0.f;
  // logits bounded (|L| <~ 5) -> no max-subtraction needed; clamp is a no-op on sane data.
  for(int phase = 0; phase < 2; phase++){
    for(int mt = 0; mt < 8; mt++){
      const int mcol = wv*128 + mt*16 + l15;
      float L[6][4];
      for(int o = 0; o < 6; o++){ float c0 = cb[o]; for(int r = 0; r < 4; r++) L[o][r] = c0; }
      #pragma unroll
      for(int h = 0; h < 6; h++){
        const size_t krow = (((size_t)(b*6 + h)) * 512 + mcol) * 64 + quad*8;
        bf16x8 kf0 = ld16(kb + krow),  kf1 = ld16(kb + krow + 32);
        bf16x8 af0 = ld16(akb + krow), af1 = ld16(akb + krow + 32);
        bf16x8 qf0 = ld16(&qt[h][l15][quad*8]), qf1 = ld16(&qt[h][l15][32 + quad*8]);
        bf16x8 gf0 = ld16(&at[h][l15][quad*8]), gf1 = ld16(&at[h][l15][32 + quad*8]);
        f32x4 qk = fzero(); qk = mm(qf0, kf0, qk); qk = mm(qf1, kf1, qk);
        f32x4 dd = fzero(); dd = mm(gf0, af0, dd); dd = mm(gf1, af1, dd);
        float kn = kn4[(b*6 + h)*512 + mcol];
        #pragma unroll
        for(int r = 0; r < 4; r++){
          float q_ = qk[r];
          float e  = q_ * sc;
          float d2 = qn4r[h][r] + kn - 2.f * q_ * q_;
          float ri = rs * sqrtf(fmaxf(d2, 0.f));
          float g  = gs * dd[r] * dd[r];
          #pragma unroll
          for(int o = 0; o < 6; o++)
            L[o][r] += cw[o*18 + h]*e + cw[o*18 + 6 + h]*ri + cw[o*18 + 12 + h]*g;
        }
      }
      if(phase == 0){
        for(int o = 0; o < 6; o++) for(int r = 0; r < 4; r++) S[o][r] += __expf(fminf(L[o][r], 80.f));
      } else {
        for(int o = 0; o < 6; o++) for(int r = 0; r < 4; r++){
          float a = __expf(fminf(L[o][r], 80.f)) * recS[o][r];
          attn[(((size_t)(b*6 + o)) * 512 + (n0 + quad*4 + r)) * 512 + mcol] = a;
        }
      }
    }
    if(phase == 0){
      for(int o = 0; o < 6; o++) for(int r = 0; r < 4; r++){
        float s = S[o][r];
        s += __shfl_xor(s, 1); s += __shfl_xor(s, 2); s += __shfl_xor(s, 4); s += __shfl_xor(s, 8);
        if(l15 == 0) red[o][quad*4 + r][wv] = s;
      }
      __syncthreads();
      for(int o = 0; o < 6; o++) for(int r = 0; r < 4; r++){
        int rw = quad*4 + r;
        recS[o][r] = 1.f / (red[o][rw][0] + red[o][rw][1] + red[o][rw][2] + red[o][rw][3]);
      }
      __syncthreads();
    }
  }
}

// ---------------- out = attn(f32) @ v per (b,h), scatter to [B,N,C] bf16 ----------------
__global__ __launch_bounds__(256,2) void k_av(const float* __restrict__ attn, const u16* __restrict__ vb,
                                              u16* __restrict__ av)
{
  __shared__ __align__(16) u16 At[128][72];
  __shared__ __align__(16) u16 Vt[64][72];   // v transposed: Vt[d][k]
  const int tid = threadIdx.x, wv = tid >> 6, lane = tid & 63, quad = lane >> 4, l15 = lane & 15;
  const int blk = blockIdx.x, bh = blk >> 2, n0 = (blk & 3) * 128;
  const int b = bh / 6, h = bh - b * 6;
  const float* Ap = attn + ((size_t)bh * 512 + n0) * 512;
  const u16* Vp = vb + (size_t)bh * 512 * 64;
  f32x4 acc[2][4];
  for(int mt = 0; mt < 2; mt++) for(int nt = 0; nt < 4; nt++) acc[mt][nt] = fzero();
  for(int k0 = 0; k0 < 512; k0 += 64){
    for(int i = 0; i < 4; i++){ int c = tid + i*256; int row = c >> 3, col = (c & 7) * 8;
      *(uint4*)&At[row][col] = cvt8(&Ap[(size_t)row*512 + k0 + col]); }
    for(int i = 0; i < 2; i++){ int c = tid + i*256; int kk = c >> 3, d0 = (c & 7) * 8;
      V16 cu; cu.u = *(const uint4*)&Vp[(size_t)(k0 + kk)*64 + d0];
      for(int j = 0; j < 8; j++) Vt[d0 + j][kk] = cu.h[j]; }
    __syncthreads();
    for(int hf = 0; hf < 2; hf++){
      bf16x8 af[2], bfv[4];
      for(int mt = 0; mt < 2; mt++) af[mt]  = ld16(&At[wv*32 + mt*16 + l15][hf*32 + quad*8]);
      for(int nt = 0; nt < 4; nt++) bfv[nt] = ld16(&Vt[nt*16 + l15][hf*32 + quad*8]);
      for(int mt = 0; mt < 2; mt++) for(int nt = 0; nt < 4; nt++)
        acc[mt][nt] = mm(af[mt], bfv[nt], acc[mt][nt]);
    }
    __syncthreads();
  }
  for(int mt = 0; mt < 2; mt++) for(int nt = 0; nt < 4; nt++) for(int r = 0; r < 4; r++){
    int n = n0 + wv*32 + mt*16 + quad*4 + r, d = nt*16 + l15;
    av[((size_t)(b*512 + n)) * 384 + h*64 + d] = f2b(acc[mt][nt][r]);
  }
}

extern "C" void kernel_launch(void* const* d_in, const int* in_sizes, int n_in,
                              void* d_out, int out_size, void* d_ws, size_t ws_size,
                              hipStream_t stream) {
  (void)in_sizes; (void)n_in; (void)out_size; (void)ws_size;
  const float* src    = (const float*)d_in[0];
  const float* pre_w  = (const float*)d_in[1];
  const float* pre_b  = (const float*)d_in[2];
  const float* qkv_w  = (const float*)d_in[3];
  const float* qkv_b  = (const float*)d_in[4];
  const float* scp    = (const float*)d_in[5];
  const float* rsp    = (const float*)d_in[6];
  const float* gsp    = (const float*)d_in[7];
  const float* convw  = (const float*)d_in[8];
  const float* convb  = (const float*)d_in[9];
  const float* proj_w = (const float*)d_in[10];
  const float* proj_b = (const float*)d_in[11];
  const float* n1w    = (const float*)d_in[12];
  const float* n1b    = (const float*)d_in[13];
  const float* l1w    = (const float*)d_in[14];
  const float* l1b    = (const float*)d_in[15];
  const float* l2w    = (const float*)d_in[16];
  const float* l2b    = (const float*)d_in[17];

  char* ws = (char*)d_ws;
  // liveness-packed workspace (peak 36.4 MiB)
  u16*   xb   = (u16*)(ws + 0);            // [8192,384] bf16 ; later attV ; later x2b
  u16*   qb   = (u16*)(ws + 6291456);      // [B,H,N,64] bf16 ; region later y1 then hb
  u16*   kb_  = (u16*)(ws + 12582912);
  u16*   vb   = (u16*)(ws + 18874368);
  u16*   aqb  = (u16*)(ws + 25165824);     // region later x2f
  u16*   akb  = (u16*)(ws + 31457280);
  float* qn4  = (float*)(ws + 37748736);
  float* kn4  = (float*)(ws + 37945344);
  float* y1   = (float*)(ws + 6291456);    // [8192,384] f32 over dead q/k
  u16*   hb   = (u16*)(ws + 6291456);      // [8192,1152] bf16 over dead q/k/v
  float* x2f  = (float*)(ws + 25165824);   // [8192,384] f32 over dead Aq/Ak
  u16*   attV = xb;
  u16*   x2b  = xb;

  float* out_src  = (float*)d_out;          // [16,512,384]
  float* out_attn = out_src + 3145728;      // [16,6,512,512]

  k_ln_src<<<2048, 256, 0, stream>>>(src, pre_w, pre_b, xb);
  k_gemm<0, 384, 1152><<<576, 256, 0, stream>>>(xb, qkv_w, qkv_b, qb, kb_, vb, nullptr, nullptr);
  k_cholqr<<<192, 256, 0, stream>>>(qb, kb_, aqb, akb, qn4, kn4);
  k_attn<<<512, 256, 0, stream>>>(qb, kb_, aqb, akb, qn4, kn4, convw, convb, scp, rsp, gsp, out_attn);
  k_av<<<384, 256, 0, stream>>>(out_attn, vb, attV);
  k_gemm<1, 384, 384><<<192, 256, 0, stream>>>(attV, proj_w, proj_b, nullptr, nullptr, nullptr, src, y1);
  k_ln_mid<<<2048, 256, 0, stream>>>(y1, n1w, n1b, x2b, x2f);
  k_gemm<2, 384, 1152><<<576, 256, 0, stream>>>(x2b, l1w, l1b, hb, nullptr, nullptr, nullptr, nullptr);
  k_gemm<1, 1152, 384><<<192, 256, 0, stream>>>(hb, l2w, l2b, nullptr, nullptr, nullptr, x2f, out_src);
}

// Round 4
// 666.154 us; speedup vs baseline: 1.2257x; 1.2257x over previous
//
#include <hip/hip_runtime.h>
#include <cstdint>
#include <cstddef>

#define DEVI static __device__ __forceinline__

typedef __bf16 bf16x8 __attribute__((ext_vector_type(8)));
typedef float f32x4 __attribute__((ext_vector_type(4)));
typedef unsigned short u16;
typedef unsigned int u32;

DEVI float b2f(u16 h){ u32 x = ((u32)h) << 16; float f; __builtin_memcpy(&f, &x, 4); return f; }
DEVI u16 f2b(float f){ u32 x; __builtin_memcpy(&x, &f, 4); u32 r = (x + 0x7FFFu + ((x >> 16) & 1u)) >> 16; return (u16)r; }

union V16 { uint4 u; bf16x8 v; u16 h[8]; };

DEVI bf16x8 ld16(const u16* p){ V16 t; t.u = *(const uint4*)p; return t.v; }
DEVI f32x4 fzero(){ f32x4 z; z[0]=0.f; z[1]=0.f; z[2]=0.f; z[3]=0.f; return z; }
DEVI f32x4 mm(bf16x8 a, bf16x8 b, f32x4 c){ return __builtin_amdgcn_mfma_f32_16x16x32_bf16(a, b, c, 0, 0, 0); }
DEVI uint4 cvt8(const float* p){
  float4 a = *(const float4*)p, b = *(const float4*)(p + 4);
  V16 t; t.h[0]=f2b(a.x); t.h[1]=f2b(a.y); t.h[2]=f2b(a.z); t.h[3]=f2b(a.w);
  t.h[4]=f2b(b.x); t.h[5]=f2b(b.y); t.h[6]=f2b(b.z); t.h[7]=f2b(b.w); return t.u;
}

// ---------------- LayerNorm (f32 in -> bf16 out) ----------------
__global__ __launch_bounds__(256) void k_ln_src(const float* __restrict__ in, const float* __restrict__ w,
                                                const float* __restrict__ bias, u16* __restrict__ out){
  int wave = threadIdx.x >> 6, lane = threadIdx.x & 63;
  int row = blockIdx.x * 4 + wave;            // 8192 rows
  const float* p = in + (size_t)row * 384;
  float v[6], s = 0.f, sq = 0.f;
  for(int i = 0; i < 6; i++){ v[i] = p[lane + 64*i]; s += v[i]; sq += v[i]*v[i]; }
  for(int off = 1; off < 64; off <<= 1){ s += __shfl_xor(s, off); sq += __shfl_xor(sq, off); }
  float mu = s * (1.f/384.f), var = sq * (1.f/384.f) - mu*mu;
  float rstd = rsqrtf(fmaxf(var, 0.f) + 1e-5f);
  for(int i = 0; i < 6; i++){
    int j = lane + 64*i;
    out[(size_t)row*384 + j] = f2b((v[i]-mu)*rstd*w[j] + bias[j]);
  }
}

// ---------------- LayerNorm (f32 in -> bf16 + f32 out) ----------------
__global__ __launch_bounds__(256) void k_ln_mid(const float* __restrict__ in, const float* __restrict__ w,
                                                const float* __restrict__ bias, u16* __restrict__ outb,
                                                float* __restrict__ outf){
  int wave = threadIdx.x >> 6, lane = threadIdx.x & 63;
  int row = blockIdx.x * 4 + wave;
  const float* p = in + (size_t)row * 384;
  float v[6], s = 0.f, sq = 0.f;
  for(int i = 0; i < 6; i++){ v[i] = p[lane + 64*i]; s += v[i]; sq += v[i]*v[i]; }
  for(int off = 1; off < 64; off <<= 1){ s += __shfl_xor(s, off); sq += __shfl_xor(sq, off); }
  float mu = s * (1.f/384.f), var = sq * (1.f/384.f) - mu*mu;
  float rstd = rsqrtf(fmaxf(var, 0.f) + 1e-5f);
  for(int i = 0; i < 6; i++){
    int j = lane + 64*i;
    float o = (v[i]-mu)*rstd*w[j] + bias[j];
    outb[(size_t)row*384 + j] = f2b(o);
    outf[(size_t)row*384 + j] = o;
  }
}

// ---------------- bf16 MFMA GEMM: C = A[M,K](bf16) @ W[N,K](f32->bf16)^T + bias(f32) ----------------
// MODE 0: scatter qkv -> q/k/v [B,H,N,64] bf16
// MODE 1: + res (f32) -> f32 out
// MODE 2: exact GELU -> bf16 out
template<int MODE, int KDIM, int NOUT>
__global__ __launch_bounds__(256,2) void k_gemm(
    const u16* __restrict__ A, const float* __restrict__ W, const float* __restrict__ bias,
    u16* __restrict__ o0, u16* __restrict__ o1, u16* __restrict__ o2,
    const float* __restrict__ res, float* __restrict__ fout)
{
  __shared__ __align__(16) u16 As[128][72];   // +8 pad breaks bank conflicts
  __shared__ __align__(16) u16 Bs[128][72];
  const int tid = threadIdx.x, wv = tid >> 6, lane = tid & 63, quad = lane >> 4, l15 = lane & 15;
  constexpr int NB = NOUT / 128;
  const int m0 = (blockIdx.x / NB) * 128, n0 = (blockIdx.x % NB) * 128;
  const int wr = (wv >> 1) * 64, wc = (wv & 1) * 64;
  f32x4 acc[4][4];
  for(int i = 0; i < 4; i++) for(int j = 0; j < 4; j++) acc[i][j] = fzero();
  for(int kt = 0; kt < KDIM; kt += 64){
    for(int i = 0; i < 4; i++){
      int c = tid + i*256; int row = c >> 3, col = (c & 7) * 8;
      *(uint4*)&As[row][col] = *(const uint4*)&A[(size_t)(m0+row)*KDIM + kt + col];
      *(uint4*)&Bs[row][col] = cvt8(&W[(size_t)(n0+row)*KDIM + kt + col]);
    }
    __syncthreads();
    for(int hf = 0; hf < 2; hf++){
      bf16x8 af[4], bf_[4];
      for(int t = 0; t < 4; t++) af[t]  = ld16(&As[wr + t*16 + l15][hf*32 + quad*8]);
      for(int t = 0; t < 4; t++) bf_[t] = ld16(&Bs[wc + t*16 + l15][hf*32 + quad*8]);
      for(int mt = 0; mt < 4; mt++) for(int nt = 0; nt < 4; nt++)
        acc[mt][nt] = mm(af[mt], bf_[nt], acc[mt][nt]);
    }
    __syncthreads();
  }
  for(int mt = 0; mt < 4; mt++) for(int nt = 0; nt < 4; nt++){
    const int gcol = n0 + wc + nt*16 + l15;
    const float bv = bias[gcol];
    for(int r = 0; r < 4; r++){
      const int grow = m0 + wr + mt*16 + quad*4 + r;
      float val = acc[mt][nt][r] + bv;
      if constexpr(MODE == 0){
        int s = gcol / 384, rem = gcol - s*384, h = rem >> 6, d = rem & 63;
        int bb = grow >> 9, n = grow & 511;
        u16* t = (s == 0) ? o0 : ((s == 1) ? o1 : o2);
        t[(((size_t)(bb*6 + h))*512 + n)*64 + d] = f2b(val);
      } else if constexpr(MODE == 1){
        val += res[(size_t)grow*384 + gcol];
        fout[(size_t)grow*384 + gcol] = val;
      } else {
        float g = 0.5f * val * (1.f + erff(val * 0.70710678118654752f));
        o0[(size_t)grow*1152 + gcol] = f2b(g);
      }
    }
  }
}

// ---------------- Cholesky-QR per (b,h): Aq = q * R^{-1}, plus ||row||^4 (round-2 proven version) ----------------
__global__ __launch_bounds__(256,1) void k_cholqr(
    const u16* __restrict__ qb, const u16* __restrict__ kb,
    u16* __restrict__ aqb, u16* __restrict__ akb,
    float* __restrict__ qn4, float* __restrict__ kn4)
{
  __shared__ float G[64][65];
  __shared__ float invd[64];
  const int tid = threadIdx.x, wv = tid >> 6, lane = tid & 63, quad = lane >> 4, l15 = lane & 15;
  const int blk = blockIdx.x;                 // 0..191: first 96 = q, next 96 = k
  const int isk = blk >= 96; const int bh = isk ? blk - 96 : blk;
  const u16* M = (isk ? kb : qb) + (size_t)bh * 512 * 64;
  u16* Ao = (isk ? akb : aqb) + (size_t)bh * 512 * 64;
  float* n4 = (isk ? kn4 : qn4) + bh * 512;
  for(int rr = tid; rr < 512; rr += 256){
    const u16* p = M + (size_t)rr * 64;
    float s = 0.f;
    for(int i = 0; i < 8; i++){ V16 c; c.u = *(const uint4*)&p[i*8];
      for(int j = 0; j < 8; j++){ float x = b2f(c.h[j]); s += x*x; } }
    n4[rr] = s * s;
  }
  // Gram G = M^T M via MFMA (strided gathers; tiny volume)
  f32x4 g4[4];
  for(int jt = 0; jt < 4; jt++) g4[jt] = fzero();
  for(int k0 = 0; k0 < 512; k0 += 32){
    const u16* base = M + (size_t)(k0 + quad*8) * 64;
    V16 a;
    for(int j = 0; j < 8; j++) a.h[j] = base[(size_t)j*64 + wv*16 + l15];
    for(int jt = 0; jt < 4; jt++){
      V16 bb;
      for(int j = 0; j < 8; j++) bb.h[j] = base[(size_t)j*64 + jt*16 + l15];
      g4[jt] = mm(a.v, bb.v, g4[jt]);
    }
  }
  for(int jt = 0; jt < 4; jt++)
    for(int r = 0; r < 4; r++)
      G[wv*16 + quad*4 + r][jt*16 + l15] = g4[jt][r];
  __syncthreads();
  // Cholesky (upper R; guarded pivots)
  for(int k = 0; k < 64; k++){
    if(tid == 0){ float pv = sqrtf(fmaxf(G[k][k], 1e-12f)); G[k][k] = pv; invd[k] = 1.f / pv; }
    __syncthreads();
    if(tid > k && tid < 64) G[k][tid] *= invd[k];
    __syncthreads();
    float gkl = G[k][lane];
    for(int i = k + 1 + wv; i < 64; i += 4)
      G[i][lane] -= G[k][i] * gkl;
    __syncthreads();
  }
  // per-row solve y R = m (forward substitution, fully unrolled)
  for(int rr = tid; rr < 512; rr += 256){
    float m[64];
    const u16* p = M + (size_t)rr * 64;
    for(int i = 0; i < 8; i++){ V16 c; c.u = *(const uint4*)&p[i*8];
      for(int j = 0; j < 8; j++) m[i*8 + j] = b2f(c.h[j]); }
    #pragma unroll
    for(int j = 0; j < 64; j++){
      float yj = m[j] * invd[j];
      m[j] = yj;
      #pragma unroll
      for(int i = j + 1; i < 64; i++) m[i] -= yj * G[j][i];
    }
    for(int i = 0; i < 8; i++){ V16 c;
      for(int j = 0; j < 8; j++) c.h[j] = f2b(m[i*8 + j]);
      *(uint4*)&Ao[(size_t)rr*64 + i*8] = c.u; }
  }
}

// ---------------- Fused logits + exp (single phase): unnormalized exp -> d_out, partial sums -> ws ----------------
// grid 1024: b in low bits (XCD-local K reuse), 32 n-tiles of 16, 2 m-halves of 256
__global__ __launch_bounds__(256,2) void k_attn(
    const u16* __restrict__ qb, const u16* __restrict__ kb,
    const u16* __restrict__ aqb, const u16* __restrict__ akb,
    const float* __restrict__ qn4, const float* __restrict__ kn4,
    const float* __restrict__ convw, const float* __restrict__ convb,
    const float* __restrict__ scp, const float* __restrict__ rsp, const float* __restrict__ gsp,
    float* __restrict__ attn, float* __restrict__ Spart)
{
  __shared__ __align__(16) u16 qt[6][16][72];
  __shared__ __align__(16) u16 at[6][16][72];
  __shared__ float cw[108];
  __shared__ float cb[6];
  __shared__ float red[6][16][4];
  const int tid = threadIdx.x, wv = tid >> 6, lane = tid & 63, quad = lane >> 4, l15 = lane & 15;
  const int blk = blockIdx.x;
  const int b = ((blk & 7) << 1) | ((blk >> 3) & 1);   // XCD swizzle: 2 batches per XCD
  const int r2 = blk >> 4;                              // 0..63
  const int n0 = (r2 & 31) * 16, half = r2 >> 5;
  if(tid < 108) cw[tid] = convw[tid];
  if(tid >= 128 && tid < 134) cb[tid - 128] = convb[tid - 128];
  for(int c = tid; c < 768; c += 256){
    int h = c >> 7, rem = c & 127, row = rem >> 3, col = (rem & 7) * 8;
    size_t off = (((size_t)(b*6 + h)) * 512 + (size_t)(n0 + row)) * 64 + col;
    *(uint4*)&qt[h][row][col] = *(const uint4*)&qb[off];
    *(uint4*)&at[h][row][col] = *(const uint4*)&aqb[off];
  }
  __syncthreads();
  const float sc = scp[0], rs = rsp[0], gs = gsp[0];
  float qn4r[6][4];
  for(int h = 0; h < 6; h++)
    for(int r = 0; r < 4; r++)
      qn4r[h][r] = qn4[(b*6 + h)*512 + n0 + quad*4 + r];
  float S[6][4];
  for(int o = 0; o < 6; o++) for(int r = 0; r < 4; r++) S[o][r] = 0.f;
  for(int mt = 0; mt < 4; mt++){
    const int mcol = half*256 + wv*64 + mt*16 + l15;
    float L[6][4];
    for(int o = 0; o < 6; o++){ float c0 = cb[o]; for(int r = 0; r < 4; r++) L[o][r] = c0; }
    #pragma unroll
    for(int h = 0; h < 6; h++){
      const size_t krow = (((size_t)(b*6 + h)) * 512 + mcol) * 64 + quad*8;
      bf16x8 kf0 = ld16(kb + krow),  kf1 = ld16(kb + krow + 32);
      bf16x8 af0 = ld16(akb + krow), af1 = ld16(akb + krow + 32);
      bf16x8 qf0 = ld16(&qt[h][l15][quad*8]), qf1 = ld16(&qt[h][l15][32 + quad*8]);
      bf16x8 gf0 = ld16(&at[h][l15][quad*8]), gf1 = ld16(&at[h][l15][32 + quad*8]);
      f32x4 qk = fzero(); qk = mm(qf0, kf0, qk); qk = mm(qf1, kf1, qk);
      f32x4 dd = fzero(); dd = mm(gf0, af0, dd); dd = mm(gf1, af1, dd);
      float kn = kn4[(b*6 + h)*512 + mcol];
      #pragma unroll
      for(int r = 0; r < 4; r++){
        float q_ = qk[r];
        float e  = q_ * sc;
        float d2 = qn4r[h][r] + kn - 2.f * q_ * q_;
        float ri = rs * sqrtf(fmaxf(d2, 0.f));
        float g  = gs * dd[r] * dd[r];
        #pragma unroll
        for(int o = 0; o < 6; o++)
          L[o][r] += cw[o*18 + h]*e + cw[o*18 + 6 + h]*ri + cw[o*18 + 12 + h]*g;
      }
    }
    for(int o = 0; o < 6; o++) for(int r = 0; r < 4; r++){
      float e = __expf(fminf(L[o][r], 80.f));
      S[o][r] += e;
      attn[(((size_t)(b*6 + o)) * 512 + (n0 + quad*4 + r)) * 512 + mcol] = e;
    }
  }
  for(int o = 0; o < 6; o++) for(int r = 0; r < 4; r++){
    float s = S[o][r];
    s += __shfl_xor(s, 1); s += __shfl_xor(s, 2); s += __shfl_xor(s, 4); s += __shfl_xor(s, 8);
    if(l15 == 0) red[o][quad*4 + r][wv] = s;
  }
  __syncthreads();
  if(tid < 96){
    int o = tid >> 4, rr = tid & 15;
    float s = red[o][rr][0] + red[o][rr][1] + red[o][rr][2] + red[o][rr][3];
    Spart[(((size_t)(b*6 + o)) * 512 + n0 + rr) * 2 + half] = s;
  }
}

// ---------------- out = attn @ v per (b,h): normalizes attn in-place (write-back) + PV MFMA ----------------
__global__ __launch_bounds__(256,2) void k_av(float* __restrict__ attn, const u16* __restrict__ vb,
                                              const float* __restrict__ Spart, u16* __restrict__ av)
{
  __shared__ __align__(16) u16 At[128][72];
  __shared__ __align__(16) u16 Vt[64][72];   // v transposed: Vt[d][k]
  __shared__ float recs[128];
  const int tid = threadIdx.x, wv = tid >> 6, lane = tid & 63, quad = lane >> 4, l15 = lane & 15;
  const int blk = blockIdx.x, bh = blk >> 2, n0 = (blk & 3) * 128;
  const int b = bh / 6, h = bh - b * 6;
  float* Ap = attn + ((size_t)bh * 512 + n0) * 512;
  const u16* Vp = vb + (size_t)bh * 512 * 64;
  if(tid < 128){
    size_t si = ((size_t)bh * 512 + n0 + tid) * 2;
    recs[tid] = 1.f / (Spart[si] + Spart[si + 1]);
  }
  __syncthreads();
  f32x4 acc[2][4];
  for(int mt = 0; mt < 2; mt++) for(int nt = 0; nt < 4; nt++) acc[mt][nt] = fzero();
  for(int k0 = 0; k0 < 512; k0 += 64){
    for(int i = 0; i < 4; i++){
      int c = tid + i*256; int row = c >> 3, col = (c & 7) * 8;
      float* sp = Ap + (size_t)row*512 + k0 + col;
      float rc = recs[row];
      float4 x = *(const float4*)sp, y = *(const float4*)(sp + 4);
      x.x *= rc; x.y *= rc; x.z *= rc; x.w *= rc;
      y.x *= rc; y.y *= rc; y.z *= rc; y.w *= rc;
      *(float4*)sp = x; *(float4*)(sp + 4) = y;      // normalized attn (output 1)
      V16 t; t.h[0]=f2b(x.x); t.h[1]=f2b(x.y); t.h[2]=f2b(x.z); t.h[3]=f2b(x.w);
      t.h[4]=f2b(y.x); t.h[5]=f2b(y.y); t.h[6]=f2b(y.z); t.h[7]=f2b(y.w);
      *(uint4*)&At[row][col] = t.u;
    }
    for(int i = 0; i < 2; i++){ int c = tid + i*256; int kk = c >> 3, d0 = (c & 7) * 8;
      V16 cu; cu.u = *(const uint4*)&Vp[(size_t)(k0 + kk)*64 + d0];
      for(int j = 0; j < 8; j++) Vt[d0 + j][kk] = cu.h[j]; }
    __syncthreads();
    for(int hf = 0; hf < 2; hf++){
      bf16x8 af[2], bfv[4];
      for(int mt = 0; mt < 2; mt++) af[mt]  = ld16(&At[wv*32 + mt*16 + l15][hf*32 + quad*8]);
      for(int nt = 0; nt < 4; nt++) bfv[nt] = ld16(&Vt[nt*16 + l15][hf*32 + quad*8]);
      for(int mt = 0; mt < 2; mt++) for(int nt = 0; nt < 4; nt++)
        acc[mt][nt] = mm(af[mt], bfv[nt], acc[mt][nt]);
    }
    __syncthreads();
  }
  for(int mt = 0; mt < 2; mt++) for(int nt = 0; nt < 4; nt++) for(int r = 0; r < 4; r++){
    int n = n0 + wv*32 + mt*16 + quad*4 + r, d = nt*16 + l15;
    av[((size_t)(b*512 + n)) * 384 + h*64 + d] = f2b(acc[mt][nt][r]);
  }
}

extern "C" void kernel_launch(void* const* d_in, const int* in_sizes, int n_in,
                              void* d_out, int out_size, void* d_ws, size_t ws_size,
                              hipStream_t stream) {
  (void)in_sizes; (void)n_in; (void)out_size; (void)ws_size;
  const float* src    = (const float*)d_in[0];
  const float* pre_w  = (const float*)d_in[1];
  const float* pre_b  = (const float*)d_in[2];
  const float* qkv_w  = (const float*)d_in[3];
  const float* qkv_b  = (const float*)d_in[4];
  const float* scp    = (const float*)d_in[5];
  const float* rsp    = (const float*)d_in[6];
  const float* gsp    = (const float*)d_in[7];
  const float* convw  = (const float*)d_in[8];
  const float* convb  = (const float*)d_in[9];
  const float* proj_w = (const float*)d_in[10];
  const float* proj_b = (const float*)d_in[11];
  const float* n1w    = (const float*)d_in[12];
  const float* n1b    = (const float*)d_in[13];
  const float* l1w    = (const float*)d_in[14];
  const float* l1b    = (const float*)d_in[15];
  const float* l2w    = (const float*)d_in[16];
  const float* l2b    = (const float*)d_in[17];

  char* ws = (char*)d_ws;
  // liveness-packed workspace — PEAK 37,748,736 B (< round-2-proven 38,141,952)
  // [0 .. 6.29MB):      xb (LN out)  ->  qn4/kn4/Spart (after qkv gemm)  ->  x2b (after k_av epoch)
  // [6.29 .. 12.58MB):  qb  -> y1 low half  -> hb low
  // [12.58 .. 18.87MB): kb_ -> y1 high half -> hb mid
  // [18.87 .. 25.17MB): vb  -> hb high
  // [25.17 .. 31.46MB): aqb -> attV -> x2f low half
  // [31.46 .. 37.75MB): akb -> x2f high half
  u16*   xb   = (u16*)(ws + 0);
  u16*   qb   = (u16*)(ws + 6291456);
  u16*   kb_  = (u16*)(ws + 12582912);
  u16*   vb   = (u16*)(ws + 18874368);
  u16*   aqb  = (u16*)(ws + 25165824);
  u16*   akb  = (u16*)(ws + 31457280);
  float* qn4  = (float*)(ws + 0);          // over dead xb (xb dead after qkv gemm)
  float* kn4  = (float*)(ws + 196608);
  float* Spart= (float*)(ws + 393216);     // [16,6,512,2] f32, dead after k_av
  u16*   attV = (u16*)(ws + 25165824);     // over dead aqb (dead after k_attn)
  float* y1   = (float*)(ws + 6291456);    // over dead qb/kb_ (dead after k_attn)
  u16*   x2b  = (u16*)(ws + 0);            // over dead qn4/kn4/Spart
  float* x2f  = (float*)(ws + 25165824);   // over dead attV (dead after proj gemm)
  u16*   hb   = (u16*)(ws + 6291456);      // over dead y1/vb

  float* out_src  = (float*)d_out;          // [16,512,384]
  float* out_attn = out_src + 3145728;      // [16,6,512,512]

  k_ln_src<<<2048, 256, 0, stream>>>(src, pre_w, pre_b, xb);
  k_gemm<0, 384, 1152><<<576, 256, 0, stream>>>(xb, qkv_w, qkv_b, qb, kb_, vb, nullptr, nullptr);
  k_cholqr<<<192, 256, 0, stream>>>(qb, kb_, aqb, akb, qn4, kn4);
  k_attn<<<1024, 256, 0, stream>>>(qb, kb_, aqb, akb, qn4, kn4, convw, convb, scp, rsp, gsp, out_attn, Spart);
  k_av<<<384, 256, 0, stream>>>(out_attn, vb, Spart, attV);
  k_gemm<1, 384, 384><<<192, 256, 0, stream>>>(attV, proj_w, proj_b, nullptr, nullptr, nullptr, src, y1);
  k_ln_mid<<<2048, 256, 0, stream>>>(y1, n1w, n1b, x2b, x2f);
  k_gemm<2, 384, 1152><<<576, 256, 0, stream>>>(x2b, l1w, l1b, hb, nullptr, nullptr, nullptr, nullptr);
  k_gemm<1, 1152, 384><<<192, 256, 0, stream>>>(hb, l2w, l2b, nullptr, nullptr, nullptr, x2f, out_src);
}